// Round 1
// baseline (243.091 us; speedup 1.0000x reference)
//
#include <hip/hip_runtime.h>

// ANI loss: per-voxel 3x3 symmetric eigen (closed form), masked L1 reduction.
// input_data [4,6,96,96,96] f32, target [4,6,96,96,96] f32, mask [4,1,96,96,96] i32,
// gt_mean [6] f32, gt_std [6] f32  ->  scalar f32 loss.
//
// Simplification: input_ani = 3*p*cos(acos(r)/3); target_ani = q - p*cos(acos(r)/3)
// (only one cos/acos pair per tensor, no explicit l0/l1/l2).

namespace {
constexpr int SB    = 96 * 96 * 96;   // voxels per volume = 884736
constexpr int BATCH = 4;
constexpr int NVOX  = SB * BATCH;     // 3538944
constexpr int N4    = NVOX / 4;       // 884736 float4-groups
constexpr int BLOCK = 256;
constexpr int GRID  = N4 / BLOCK;     // 3456 blocks (exact)

__device__ __forceinline__ float f4get(const float4& v, int j) {
    return ((const float*)&v)[j];
}

// Returns p*cos(acos(r)/3); q via out-param. NaN-free for the all-zero tensor.
__device__ __forceinline__ float eig_pc(const float y0, const float y1, const float y2,
                                        const float y3, const float y4, const float y5,
                                        float& q_out) {
    float q  = (y0 + y3 + y5) * (1.0f / 3.0f);
    float d0 = y0 - q, d1 = y3 - q, d2 = y5 - q;
    float p2 = d0 * d0 + d1 * d1 + d2 * d2 + 2.0f * (y1 * y1 + y2 * y2 + y4 * y4);
    float p  = sqrtf(p2 * (1.0f / 6.0f));
    float ps = (p > 0.0f) ? p : 1.0f;
    float inv = 1.0f / ps;
    float b00 = d0 * inv, b11 = d1 * inv, b22 = d2 * inv;
    float b01 = y1 * inv, b02 = y2 * inv, b12 = y4 * inv;
    float det = b00 * (b11 * b22 - b12 * b12)
              - b01 * (b01 * b22 - b12 * b02)
              + b02 * (b01 * b12 - b11 * b02);
    float r = fminf(fmaxf(0.5f * det, -1.0f + 1e-7f), 1.0f - 1e-7f);
    float c = cosf(acosf(r) * (1.0f / 3.0f));
    q_out = q;
    return p * c;
}

__global__ __launch_bounds__(BLOCK) void ani_reduce(
    const float* __restrict__ in, const float* __restrict__ tg,
    const int*  __restrict__ mask,
    const float* __restrict__ gt_mean, const float* __restrict__ gt_std,
    float* __restrict__ ws) {

    // Broadcast 6-element scale/shift (uniform loads -> scalar regs).
    float st[6], mn[6];
#pragma unroll
    for (int c = 0; c < 6; ++c) { st[c] = gt_std[c]; mn[c] = gt_mean[c]; }

    float sum_abs = 0.0f;
    float sum_m   = 0.0f;

    int i = blockIdx.x * blockDim.x + threadIdx.x;   // one float4-group (4 voxels)
    for (; i < N4; i += gridDim.x * blockDim.x) {
        int v4 = i * 4;
        int b  = v4 / SB;
        int s  = v4 - b * SB;            // multiple of 4 -> 16B aligned
        int base = (b * 6) * SB + s;

        float4 xi[6], xt[6];
#pragma unroll
        for (int c = 0; c < 6; ++c) {
            xi[c] = *(const float4*)(in + base + c * SB);
            xt[c] = *(const float4*)(tg + base + c * SB);
        }
        int4 mk = *(const int4*)(mask + b * SB + s);
        int mks[4] = {mk.x, mk.y, mk.z, mk.w};

#pragma unroll
        for (int j = 0; j < 4; ++j) {
            float mf = (float)mks[j];
            float yi[6], yt[6];
#pragma unroll
            for (int c = 0; c < 6; ++c) {
                yi[c] = fmaf(f4get(xi[c], j), st[c], mn[c]) * mf;
                yt[c] = fmaf(f4get(xt[c], j), st[c], mn[c]) * mf;
            }
            float qi, qt;
            float pci = eig_pc(yi[0], yi[1], yi[2], yi[3], yi[4], yi[5], qi);
            float pct = eig_pc(yt[0], yt[1], yt[2], yt[3], yt[4], yt[5], qt);
            float ani_in = 3.0f * pci;          // i2 - 0.5*(i0+i1)
            float ani_tg = qt - pct;            // 0.5*(t0+t1)
            sum_abs += fabsf(ani_in - ani_tg) * mf;
            sum_m   += mf;
        }
    }

    // wave-64 reduction
#pragma unroll
    for (int off = 32; off > 0; off >>= 1) {
        sum_abs += __shfl_down(sum_abs, off, 64);
        sum_m   += __shfl_down(sum_m,   off, 64);
    }
    __shared__ float s_abs[BLOCK / 64];
    __shared__ float s_m[BLOCK / 64];
    int lane = threadIdx.x & 63;
    int wid  = threadIdx.x >> 6;
    if (lane == 0) { s_abs[wid] = sum_abs; s_m[wid] = sum_m; }
    __syncthreads();
    if (threadIdx.x == 0) {
        float ta = 0.0f, tm = 0.0f;
#pragma unroll
        for (int w = 0; w < BLOCK / 64; ++w) { ta += s_abs[w]; tm += s_m[w]; }
        atomicAdd(&ws[0], ta);
        atomicAdd(&ws[1], tm);
    }
}

__global__ void ani_finalize(const float* __restrict__ ws, float* __restrict__ out) {
    out[0] = ws[0] / fmaxf(ws[1], 1.0f);
}

} // namespace

extern "C" void kernel_launch(void* const* d_in, const int* in_sizes, int n_in,
                              void* d_out, int out_size, void* d_ws, size_t ws_size,
                              hipStream_t stream) {
    const float* in      = (const float*)d_in[0];
    const float* tg      = (const float*)d_in[1];
    const int*   mask    = (const int*)d_in[2];
    const float* gt_mean = (const float*)d_in[3];
    const float* gt_std  = (const float*)d_in[4];
    float* ws  = (float*)d_ws;
    float* out = (float*)d_out;

    // d_ws is re-poisoned to 0xAA before every call — zero the accumulators.
    hipMemsetAsync(ws, 0, 2 * sizeof(float), stream);
    ani_reduce<<<GRID, BLOCK, 0, stream>>>(in, tg, mask, gt_mean, gt_std, ws);
    ani_finalize<<<1, 1, 0, stream>>>(ws, out);
}